// Round 18
// baseline (7658.035 us; speedup 1.0000x reference)
//
#include <hip/hip_runtime.h>
#include <hip/hip_bf16.h>
#include <stdint.h>

#define T_STEPS 512
#define NBATCH 64
#define HID 1024
#define NGATE 4096
#define NLAYERS 2
#define BH (NBATCH * HID)            // 65536
#define TBH (T_STEPS * NBATCH * HID) // 33554432
#define WEL ((size_t)NLAYERS * NGATE * HID)
#define GBLK 128                     // blocks per barrier group

typedef __attribute__((ext_vector_type(8))) short short8;
typedef __attribute__((ext_vector_type(4))) float f32x4;

__device__ __forceinline__ ushort f2bf(float f) {
  union { float f; uint32_t i; } u; u.f = f;
  return (ushort)((u.i + 0x7fffu + ((u.i >> 16) & 1u)) >> 16);  // RNE
}
__device__ __forceinline__ void gll16(const void* g, void* l) {
  __builtin_amdgcn_global_load_lds(
      (const __attribute__((address_space(1))) unsigned int*)g,
      (__attribute__((address_space(3))) unsigned int*)l, 16, 0, 0);
}

// ---- Coalesced A-staging pipeline (r18) ----
// r16 ablation: A-load phase = 8.6us/step, and r17 proved it is L2-request-
// throughput-bound (16x 64B transactions per register load). Fix: stage A via
// global_load_lds in 1KB-contiguous pieces (8x 128B full-line transactions),
// XOR-pre-swizzled source so fragment ds_reads are conflict-free; consume
// fragments from LDS. 3-buffer rotation, counted vmcnt at chunk granularity.
// Chunk = 64 k-elements (128B/row); wave stages its own 16 rows (2 gll16).
#define STAGE(C, Sp) \
  gll16(Sp + aoffs0 + (C) * 64, AbD + ((C) % 3) * 8192); \
  gll16(Sp + aoffs1 + (C) * 64, AbD + ((C) % 3) * 8192 + 1024);
#define GW(N) { asm volatile("s_waitcnt vmcnt(" #N ")" ::: "memory"); \
                __builtin_amdgcn_sched_barrier(0); }
#define CONL(C, S, KB) { \
  const short8 av  = *(const short8*)(AbR + ((C) % 3) * 8192 + ((((S) * 64) + kb4) ^ asw)); \
  const short8 b0v = *(const short8*)(bb0 + ((((KB) + (C) * 2 + (S)) * 64 + kb) ^ bsw)); \
  const short8 b1v = *(const short8*)(bb1 + ((((KB) + (C) * 2 + (S)) * 64 + kb) ^ bsw)); \
  accA = __builtin_amdgcn_mfma_f32_16x16x32_bf16(av, b0v, accA, 0, 0, 0); \
  accB = __builtin_amdgcn_mfma_f32_16x16x32_bf16(av, b1v, accB, 0, 0, 0); }
#define CONSUME(C, KB) CONL(C, 0, KB) CONL(C, 1, KB)

// One K=1024 half: 16 chunks, depth-2 prefetch (3 bufs), counted vmcnt.
#define HALF(Sp, KB) \
  STAGE(0,Sp) STAGE(1,Sp) STAGE(2,Sp) \
  GW(4) CONSUME(0,(KB))  STAGE(3,Sp)  \
  GW(4) CONSUME(1,(KB))  STAGE(4,Sp)  \
  GW(4) CONSUME(2,(KB))  STAGE(5,Sp)  \
  GW(4) CONSUME(3,(KB))  STAGE(6,Sp)  \
  GW(4) CONSUME(4,(KB))  STAGE(7,Sp)  \
  GW(4) CONSUME(5,(KB))  STAGE(8,Sp)  \
  GW(4) CONSUME(6,(KB))  STAGE(9,Sp)  \
  GW(4) CONSUME(7,(KB))  STAGE(10,Sp) \
  GW(4) CONSUME(8,(KB))  STAGE(11,Sp) \
  GW(4) CONSUME(9,(KB))  STAGE(12,Sp) \
  GW(4) CONSUME(10,(KB)) STAGE(13,Sp) \
  GW(4) CONSUME(11,(KB)) STAGE(14,Sp) \
  GW(4) CONSUME(12,(KB)) STAGE(15,Sp) \
  GW(4) CONSUME(13,(KB)) \
  GW(2) CONSUME(14,(KB)) \
  GW(0) CONSUME(15,(KB))

// ---------------- elementwise helpers ----------------
__global__ void k_f32_to_bf16(const float* __restrict__ in, ushort* __restrict__ out, int n) {
  int i = (blockIdx.x * blockDim.x + threadIdx.x) * 4;
  if (i >= n) return;
  const float4 v = *reinterpret_cast<const float4*>(in + i);
  ushort4 o; o.x = f2bf(v.x); o.y = f2bf(v.y); o.z = f2bf(v.z); o.w = f2bf(v.w);
  *reinterpret_cast<ushort4*>(out + i) = o;
}
__global__ void k_zero(int* p, int n) {
  int i = blockIdx.x * blockDim.x + threadIdx.x;
  if (i < n) p[i] = 0;
}

// ---------------- persistent fused scan (r13 structure, LDS-staged A) ----------------
struct ScanP {
  const ushort* wih; const ushort* whh;
  const ushort* xb;  const ushort* hinit;
  ushort* h0r;                            // layer-0 h ring (T_STEPS slots)
  ushort* h1r;                            // layer-1 h ring (T_STEPS slots)
  const float* c0; const float* bi; const float* bh;
  float* out; int* bar;
};

__device__ __forceinline__ void garrive(int* gb, int stripe) {
  __syncthreads();
  if (threadIdx.x == 0)
    __hip_atomic_fetch_add(gb + stripe * 16, 1, __ATOMIC_RELAXED, __HIP_MEMORY_SCOPE_AGENT);
}
__device__ __forceinline__ void gwait(int* gb, int target, bool isRoot) {
  if (threadIdx.x == 0) {
    if (isRoot) {
      const int need = target * GBLK;
      for (;;) {
        int sum = 0;
#pragma unroll
        for (int i = 0; i < 16; ++i)
          sum += __hip_atomic_load(gb + i * 16, __ATOMIC_RELAXED, __HIP_MEMORY_SCOPE_AGENT);
        if (sum >= need) break;
        __builtin_amdgcn_s_sleep(1);
      }
      __hip_atomic_store(gb + 256, target, __ATOMIC_RELAXED, __HIP_MEMORY_SCOPE_AGENT);
    } else {
      while (__hip_atomic_load(gb + 256, __ATOMIC_RELAXED, __HIP_MEMORY_SCOPE_AGENT) < target)
        __builtin_amdgcn_s_sleep(2);
    }
  }
  __syncthreads();
  __builtin_amdgcn_sched_barrier(0);
}

// 256 blocks x 256 threads. Group 0 = layer 0 (sprints ahead); group 1 = layer 1
// (one-way gated on rel0). Per step: EARLY half (dependency-free) overlaps
// barrier detection; own-group wait; LATE half; transpose; epilogue; arrive.
__global__ __launch_bounds__(256, 1) void k_scan(ScanP p) {
  __shared__ __align__(16) ushort Wl[32 * 2048];   // 128 KB
  __shared__ __align__(16) char Abuf[3 * 8192];    // 24 KB A-chunk bufs; glds overlays
  float* glds = (float*)Abuf;
  const int tid = threadIdx.x, wave = tid >> 6, lane = tid & 63;
  const bool isL1 = blockIdx.x >= 128;
  const int cb = isL1 ? (int)blockIdx.x - 128 : (int)blockIdx.x;
  const int j0 = cb * 8;
  const int stripe = cb & 15;
  const bool isRoot = (cb == 0);
  int* gb = p.bar + (isL1 ? 512 : 0);
  const int* rel0 = p.bar + 256;

  const ushort* wihL = p.wih + (isL1 ? (size_t)NGATE * HID : 0);
  const ushort* whhL = p.whh + (isL1 ? (size_t)NGATE * HID : 0);
  for (int q = wave; q < 128; q += 4) {
    const int i = q >> 2, ch = q & 3;
    const ushort* base = (ch < 2) ? wihL : whhL;
    const int g = (i >> 3) * 1024 + j0 + (i & 7);
    gll16(base + (size_t)g * 1024 + (ch & 1) * 512 + (((lane * 16) ^ ((i & 7) << 4)) >> 1),
          (char*)Wl + i * 4096 + ch * 1024);
  }

  // epilogue geometry: thread owns (b = tid>>2, j = j0 + (tid&3)*2 + {0,1})
  const int eb  = tid >> 2;
  const int jl0 = (tid & 3) * 2;
  const int jj  = j0 + jl0;
  const int lofs = isL1 ? NGATE : 0;
  float creg[2], bias[4][2];
#pragma unroll
  for (int i = 0; i < 2; ++i) creg[i] = p.c0[(isL1 ? BH : 0) + eb * 1024 + jj + i];
#pragma unroll
  for (int g = 0; g < 4; ++g)
#pragma unroll
    for (int i = 0; i < 2; ++i)
      bias[g][i] = p.bi[lofs + g * 1024 + jj + i] + p.bh[lofs + g * 1024 + jj + i];

  // ---- A-staging geometry (wave-private rows, swizzled) ----
  const int rowq = lane >> 3;                               // 0..7
  const int swb  = ((lane & 7) * 16) ^ (rowq << 4);         // pre-swizzled byte in 128B row
  const size_t aoffs0 = (size_t)(wave * 16 + rowq) * 1024 + (swb >> 1);      // j=0 rows
  const size_t aoffs1 = (size_t)(wave * 16 + 8 + rowq) * 1024 + (swb >> 1);  // j=1 rows
  char* AbD = Abuf + wave * 2048;                           // uniform LDS dest base
  const int arow = wave * 16 + (lane & 15);
  const char* AbR = Abuf + arow * 128;                      // fragment read base
  const int asw = (lane & 7) << 4;                          // A-read swizzle
  const int kb4 = (lane >> 4) * 16;                         // A byte-in-64B
  const int r0 = lane & 15;
  const char* bb0 = (const char*)Wl + r0 * 4096;
  const char* bb1 = (const char*)Wl + (r0 + 16) * 4096;
  const int bsw = (r0 & 7) << 4;
  const int kb = (lane >> 4) * 16;

  int seen0 = 0;  // L1: cached rel0 watermark (thread 0 only)

  __syncthreads();  // W staged

  for (int t = 0; t < T_STEPS; ++t) {
    f32x4 accA = {0.f, 0.f, 0.f, 0.f}, accB = {0.f, 0.f, 0.f, 0.f};

    if (!isL1) {
      { const ushort* Sp = p.xb + (size_t)t * BH;           // EARLY: x_t
        HALF(Sp, 0) }
      if (t > 0) gwait(gb, t, isRoot);                      // own group t-1 done
      { const ushort* Sp = (t == 0) ? p.hinit : p.h0r + (size_t)(t - 1) * BH;
        HALF(Sp, 32) }                                      // LATE: h0[t-1]
    } else {
      if (threadIdx.x == 0 && seen0 < t + 1) {              // gate: h0[t]
        int v = __hip_atomic_load(rel0, __ATOMIC_RELAXED, __HIP_MEMORY_SCOPE_AGENT);
        while (v < t + 1) {
          __builtin_amdgcn_s_sleep(2);
          v = __hip_atomic_load(rel0, __ATOMIC_RELAXED, __HIP_MEMORY_SCOPE_AGENT);
        }
        seen0 = v;
      }
      __syncthreads();
      __builtin_amdgcn_sched_barrier(0);
      { const ushort* Sp = p.h0r + (size_t)t * BH;          // EARLY: h0[t]
        HALF(Sp, 0) }
      if (t > 0) gwait(gb, t, isRoot);                      // own group t-1 done
      { const ushort* Sp = (t == 0) ? p.hinit + BH : p.h1r + (size_t)(t - 1) * BH;
        HALF(Sp, 32) }                                      // LATE: h1[t-1]
    }

    __syncthreads();  // all waves done reading A chunks (glds overlays Abuf)

#pragma unroll
    for (int r = 0; r < 4; ++r) {
      const int row = wave * 16 + (lane >> 4) * 4 + r;
      glds[row * 33 + r0]      = accA[r];
      glds[row * 33 + 16 + r0] = accB[r];
    }
    __syncthreads();

    float hres[2];
#pragma unroll
    for (int i = 0; i < 2; ++i) {
      const int jl = jl0 + i;
      const float gi = glds[eb * 33 + jl]      + bias[0][i];
      const float gf = glds[eb * 33 + 8 + jl]  + bias[1][i];
      const float gg = glds[eb * 33 + 16 + jl] + bias[2][i];
      const float go = glds[eb * 33 + 24 + jl] + bias[3][i];
      float c = creg[i];
      const float si = 1.f / (1.f + __expf(-gi));
      const float sf = 1.f / (1.f + __expf(-gf));
      const float so = 1.f / (1.f + __expf(-go));
      const float tg = tanhf(gg);
      c = sf * c + si * tg;
      hres[i] = so * tanhf(c);
      creg[i] = c;
    }

    const uint32_t packed = (uint32_t)f2bf(hres[0]) | ((uint32_t)f2bf(hres[1]) << 16);
    ushort* hdst = (!isL1) ? (p.h0r + (size_t)t * BH) : (p.h1r + (size_t)t * BH);
    uint32_t* hw = (uint32_t*)(hdst + eb * 1024 + jj);
    __hip_atomic_store(hw, packed, __ATOMIC_RELAXED, __HIP_MEMORY_SCOPE_AGENT);
    // same-address load-back: store committed at coherence point before arrive
    uint32_t chk = __hip_atomic_load(hw, __ATOMIC_RELAXED, __HIP_MEMORY_SCOPE_AGENT);
    asm volatile("" :: "v"(chk));

    if (isL1) {
#pragma unroll
      for (int i = 0; i < 2; ++i)
        p.out[(size_t)t * BH + eb * 1024 + jj + i] = hres[i];
      if (t == T_STEPS - 1) {
#pragma unroll
        for (int i = 0; i < 2; ++i) {
          p.out[(size_t)TBH + BH + eb * 1024 + jj + i] = hres[i];
          p.out[(size_t)TBH + 3 * BH + eb * 1024 + jj + i] = creg[i];
        }
      }
    } else if (t == T_STEPS - 1) {
#pragma unroll
      for (int i = 0; i < 2; ++i) {
        p.out[(size_t)TBH + eb * 1024 + jj + i] = hres[i];
        p.out[(size_t)TBH + 2 * BH + eb * 1024 + jj + i] = creg[i];
      }
    }

    garrive(gb, stripe);
  }

  // tail publisher: L1 steps 510/511 need rel0 beyond the in-loop publish.
  if (!isL1 && isRoot && threadIdx.x == 0) {
    const int need = T_STEPS * GBLK;
    for (;;) {
      int sum = 0;
#pragma unroll
      for (int i = 0; i < 16; ++i)
        sum += __hip_atomic_load(gb + i * 16, __ATOMIC_RELAXED, __HIP_MEMORY_SCOPE_AGENT);
      if (sum >= need) break;
      __builtin_amdgcn_s_sleep(1);
    }
    __hip_atomic_store(gb + 256, T_STEPS + 1, __ATOMIC_RELAXED, __HIP_MEMORY_SCOPE_AGENT);
  }
}

// ---------------- host ----------------
extern "C" void kernel_launch(void* const* d_in, const int* in_sizes, int n_in,
                              void* d_out, int out_size, void* d_ws, size_t ws_size,
                              hipStream_t stream) {
  const float* x    = (const float*)d_in[0];
  const float* h0   = (const float*)d_in[1];
  const float* c0   = (const float*)d_in[2];
  const float* w_ih = (const float*)d_in[3];
  const float* w_hh = (const float*)d_in[4];
  const float* b_ih = (const float*)d_in[5];
  const float* b_hh = (const float*)d_in[6];
  float* out = (float*)d_out;

  ushort* xb    = (ushort*)d_ws;
  ushort* wihb  = xb + (size_t)TBH;
  ushort* whhb  = wihb + WEL;
  ushort* hinit = whhb + WEL;
  ushort* h0r   = hinit + 2 * (size_t)BH;            // ring: T_STEPS slots
  ushort* h1r   = h0r + (size_t)TBH;                 // ring: T_STEPS slots
  int*    bar   = (int*)(h1r + (size_t)TBH);

  const size_t need = ((size_t)3 * TBH + 2 * WEL + 2 * (size_t)BH) * 2 + 4096;
  if (ws_size < need) return;  // loud failure: d_out stays poisoned

  { int n = TBH;        k_f32_to_bf16<<<(n / 4 + 255) / 256, 256, 0, stream>>>(x, xb, n); }
  { int n = (int)WEL;   k_f32_to_bf16<<<(n / 4 + 255) / 256, 256, 0, stream>>>(w_ih, wihb, n); }
  { int n = (int)WEL;   k_f32_to_bf16<<<(n / 4 + 255) / 256, 256, 0, stream>>>(w_hh, whhb, n); }
  { int n = 2 * BH;     k_f32_to_bf16<<<(n / 4 + 255) / 256, 256, 0, stream>>>(h0, hinit, n); }
  k_zero<<<4, 256, 0, stream>>>(bar, 1024);

  ScanP sp;
  sp.wih = wihb; sp.whh = whhb;
  sp.xb = xb; sp.hinit = hinit;
  sp.h0r = h0r; sp.h1r = h1r;
  sp.c0 = c0; sp.bi = b_ih; sp.bh = b_hh;
  sp.out = out; sp.bar = bar;

  void* kp[1] = {&sp};
  hipLaunchCooperativeKernel(reinterpret_cast<void*>(&k_scan),
                             dim3(256), dim3(256), kp, 0, stream);
}